// Round 4
// baseline (100.863 us; speedup 1.0000x reference)
//
#include <hip/hip_runtime.h>
#include <stdint.h>

using short8 = __attribute__((ext_vector_type(8))) short;
using f32x4  = __attribute__((ext_vector_type(4))) float;

#define OUT_F 11008
#define IN_F  4096
#define TOK   64
#define WPR   (IN_F/8)        // 512 packed words per weight row
#define BN    128
#define KSPLIT 8
#define KQ    (IN_F/KSPLIT)   // 512 k per block
#define BK    256             // k-chunk staged in LDS
#define NCH   (KQ/BK)         // 2
#define NBLK  (OUT_F/BN)      // 86
#define PARTF (TOK*OUT_F)     // 704512 floats per k-split partial

__device__ __forceinline__ unsigned short f2bf(float f) {
    uint32_t u = __float_as_uint(f);
    u += 0x7FFFu + ((u >> 16) & 1u);   // round-to-nearest-even
    return (unsigned short)(u >> 16);
}

// 8 packed sign bits (MSB-first: k=j uses bit 7-j) -> 8 bf16 in {-1,+1}
__device__ __forceinline__ short8 unpack_w(uint32_t w) {
    union { short8 v; uint32_t u[4]; } r;
#pragma unroll
    for (int p = 0; p < 4; ++p) {
        uint32_t lo = (w << (8  + 2*p)) & 0x8000u;      // bit for k=2p   -> bit15
        uint32_t hi = (w << (25 + 2*p)) & 0x80000000u;  // bit for k=2p+1 -> bit31
        r.u[p] = 0xBF80BF80u ^ lo ^ hi;                 // bit=1 -> +1 (0x3F80), 0 -> -1
    }
    return r.v;
}

__global__ __launch_bounds__(256) void gemm_kernel(const float* __restrict__ x,
                                                   const uint32_t* __restrict__ bp,
                                                   const float* __restrict__ scale,
                                                   float* __restrict__ pw) {
    // x tile [64 rows][256 k] bf16, XOR-swizzled: byte addr ^= (row&7)<<4
    __shared__ __align__(128) unsigned char xs[TOK * BK * 2];   // 32 KB

    const int bid  = blockIdx.x;
    const int nblk = bid % NBLK;
    const int q    = bid / NBLK;        // k-split index 0..7
    const int n0   = nblk * BN;
    const int tid  = threadIdx.x;
    const int wv   = tid >> 6;
    const int lane = tid & 63;
    const int l15  = lane & 15;
    const int lg   = lane >> 4;

    // ---- prefetch ALL bp words for this block into registers (32/lane) ----
    // word index within row: q*(KQ/8) + c*32 + kk*4 + lg
    const uint32_t* b0p = bp + (size_t)(n0 + wv*32 + l15) * WPR + q*(KQ/8) + lg;
    const uint32_t* b1p = b0p + 16 * WPR;
    uint32_t wA[NCH][8], wB[NCH][8];
#pragma unroll
    for (int c = 0; c < NCH; ++c)
#pragma unroll
        for (int kk = 0; kk < 8; ++kk) {
            wA[c][kk] = b0p[c*32 + kk*4];
            wB[c][kk] = b1p[c*32 + kk*4];
        }
    const float sc0 = scale[n0 + wv*32 + l15];
    const float sc1 = scale[n0 + wv*32 + 16 + l15];

    f32x4 acc[2][4];
#pragma unroll
    for (int nf = 0; nf < 2; ++nf)
#pragma unroll
        for (int mt = 0; mt < 4; ++mt) acc[nf][mt] = (f32x4){0.f, 0.f, 0.f, 0.f};

    for (int c = 0; c < NCH; ++c) {
        if (c) __syncthreads();            // all waves done reading before overwrite
        // ---- stage 64x256 fp32 -> bf16 into swizzled LDS ----
        const float* xc = x + q*KQ + c*BK;
#pragma unroll
        for (int it = 0; it < 16; ++it) {
            int f  = tid + it*256;         // float4 index in 64x64 tile of float4s
            int r  = f >> 6;               // token row 0..63 (one row per wave per it)
            int c4 = f & 63;               // float4 within row
            float4 v = *(const float4*)(xc + (size_t)r*IN_F + c4*4);
            uint32_t lo = (uint32_t)f2bf(v.x) | ((uint32_t)f2bf(v.y) << 16);
            uint32_t hi = (uint32_t)f2bf(v.z) | ((uint32_t)f2bf(v.w) << 16);
            int a = (r*512 + c4*8) ^ ((r & 7) << 4);
            *(uint2*)(xs + a) = make_uint2(lo, hi);
        }
        __syncthreads();

        // ---- compute chunk c: weights already in registers ----
#pragma unroll
        for (int kk = 0; kk < 8; ++kk) {
            short8 b0 = unpack_w(wA[c][kk]);
            short8 b1 = unpack_w(wB[c][kk]);
#pragma unroll
            for (int mt = 0; mt < 4; ++mt) {
                int row = mt*16 + l15;
                int ba  = (row*512 + kk*64 + lg*16) ^ ((row & 7) << 4);
                short8 af = *(const short8*)(xs + ba);   // conflict-free ds_read_b128
                acc[0][mt] = __builtin_amdgcn_mfma_f32_16x16x32_bf16(af, b0, acc[0][mt], 0, 0, 0);
                acc[1][mt] = __builtin_amdgcn_mfma_f32_16x16x32_bf16(af, b1, acc[1][mt], 0, 0, 0);
            }
        }
    }

    // ---- epilogue: scale + plain stores of k-split partials ----
    float* base = pw + (size_t)q * PARTF;
#pragma unroll
    for (int mt = 0; mt < 4; ++mt)
#pragma unroll
        for (int j = 0; j < 4; ++j) {
            int m = mt*16 + lg*4 + j;      // token index (D: row=(l>>4)*4+reg)
            base[(size_t)m*OUT_F + n0 + wv*32 + l15]      = acc[0][mt][j]*sc0;
            base[(size_t)m*OUT_F + n0 + wv*32 + 16 + l15] = acc[1][mt][j]*sc1;
        }
}

__global__ __launch_bounds__(256) void reduce_kernel(const float4* __restrict__ pw,
                                                     float4* __restrict__ out) {
    int i = blockIdx.x * 256 + threadIdx.x;     // float4 index, PARTF/4 = 176128 total
    float4 s = pw[i];
#pragma unroll
    for (int qq = 1; qq < KSPLIT; ++qq) {
        float4 t = pw[(size_t)qq*(PARTF/4) + i];
        s.x += t.x; s.y += t.y; s.z += t.z; s.w += t.w;
    }
    out[i] = s;
}

extern "C" void kernel_launch(void* const* d_in, const int* in_sizes, int n_in,
                              void* d_out, int out_size, void* d_ws, size_t ws_size,
                              hipStream_t stream) {
    const float*    x     = (const float*)d_in[0];
    const uint32_t* bp    = (const uint32_t*)d_in[1];
    const float*    scale = (const float*)d_in[2];
    float* pw = (float*)d_ws;                    // 8 * 704512 * 4B = 22.5 MB partials

    gemm_kernel<<<dim3(NBLK*KSPLIT), dim3(256), 0, stream>>>(x, bp, scale, pw);
    reduce_kernel<<<dim3((PARTF/4)/256), dim3(256), 0, stream>>>((const float4*)pw,
                                                                 (float4*)d_out);
}

// Round 9
// 98.039 us; speedup vs baseline: 1.0288x; 1.0288x over previous
//
#include <hip/hip_runtime.h>
#include <stdint.h>

using short8 = __attribute__((ext_vector_type(8))) short;
using f32x4  = __attribute__((ext_vector_type(4))) float;

#define OUT_F 11008
#define IN_F  4096
#define TOK   64
#define WPR   (IN_F/8)        // 512 packed words per weight row (8 bits per int32!)
#define BN    128
#define KSPLIT 4
#define KQ    (IN_F/KSPLIT)   // 1024 k-bits per block
#define BK    256             // x k-chunk staged in LDS
#define NCH   (KQ/BK)         // 4
#define NBLK  (OUT_F/BN)      // 86
#define PARTF (TOK*OUT_F)     // 704512 elems per k-split partial plane

__device__ __forceinline__ unsigned short f2bf(float f) {
    uint32_t u = __float_as_uint(f);
    u += 0x7FFFu + ((u >> 16) & 1u);   // round-to-nearest-even
    return (unsigned short)(u >> 16);
}

// one bp word = 8 sign bits in the LOW byte, MSB-first (k=j uses bit 7-j)
// -> 8 bf16 in {-1,+1}
__device__ __forceinline__ short8 unpack_w(uint32_t w) {
    union { short8 v; uint32_t u[4]; } r;
#pragma unroll
    for (int p = 0; p < 4; ++p) {
        uint32_t lo = (w << (8  + 2*p)) & 0x8000u;      // k=2p   -> bit15
        uint32_t hi = (w << (25 + 2*p)) & 0x80000000u;  // k=2p+1 -> bit31
        r.u[p] = 0xBF80BF80u ^ lo ^ hi;                 // bit=1 -> +1, 0 -> -1
    }
    return r.v;
}

__global__ __launch_bounds__(256) void gemm_kernel(const float* __restrict__ x,
                                                   const uint32_t* __restrict__ bp,
                                                   const float* __restrict__ scale,
                                                   unsigned short* __restrict__ pw) {
    // x tile [64 rows][256 k] bf16, XOR-swizzled: byte addr ^= (row&7)<<4
    __shared__ __align__(128) unsigned char xs[TOK * BK * 2];   // 32 KB

    const int bid  = blockIdx.x;
    const int nblk = bid % NBLK;
    const int q    = bid / NBLK;        // k-split index 0..3
    const int n0   = nblk * BN;
    const int tid  = threadIdx.x;
    const int wv   = tid >> 6;
    const int lane = tid & 63;
    const int l15  = lane & 15;
    const int lg   = lane >> 4;

    // ---- prefetch ALL bp words for this block into registers (64/lane) ----
    // lane's word for (nf, c, kk): row=(n0+wv*32+nf*16+l15), idx q*(KQ/8)+c*32+kk*4+lg
    // (validated addressing: passed R1 & R4 benches, absmax 0.03125)
    const uint32_t* b0p = bp + (size_t)(n0 + wv*32 + l15) * WPR + q*(KQ/8) + lg;
    const uint32_t* b1p = b0p + 16 * WPR;
    uint32_t wA[NCH][8], wB[NCH][8];
#pragma unroll
    for (int c = 0; c < NCH; ++c)
#pragma unroll
        for (int kk = 0; kk < 8; ++kk) {
            wA[c][kk] = b0p[c*32 + kk*4];
            wB[c][kk] = b1p[c*32 + kk*4];
        }
    const float sc0 = scale[n0 + wv*32 + l15];
    const float sc1 = scale[n0 + wv*32 + 16 + l15];

    f32x4 acc[2][4];
#pragma unroll
    for (int nf = 0; nf < 2; ++nf)
#pragma unroll
        for (int mt = 0; mt < 4; ++mt) acc[nf][mt] = (f32x4){0.f, 0.f, 0.f, 0.f};

#pragma unroll   // keep wA/wB indices static (runtime-indexed reg arrays -> scratch)
    for (int c = 0; c < NCH; ++c) {
        if (c) __syncthreads();            // all waves done reading before overwrite
        // ---- stage 64x256 fp32 -> bf16 into swizzled LDS (coalesced) ----
        const float* xc = x + q*KQ + c*BK;
#pragma unroll
        for (int it = 0; it < 16; ++it) {
            int r  = wv + it*4;            // one token row per wave per iter
            int c4 = lane;                 // float4 within row
            float4 v = *(const float4*)(xc + (size_t)r*IN_F + c4*4);
            uint32_t lo = (uint32_t)f2bf(v.x) | ((uint32_t)f2bf(v.y) << 16);
            uint32_t hi = (uint32_t)f2bf(v.z) | ((uint32_t)f2bf(v.w) << 16);
            int a = (r*512 + c4*8) ^ ((r & 7) << 4);
            *(uint2*)(xs + a) = make_uint2(lo, hi);
        }
        __syncthreads();

        // ---- compute chunk c: weights already in registers ----
#pragma unroll
        for (int kk = 0; kk < 8; ++kk) {
            short8 b0 = unpack_w(wA[c][kk]);
            short8 b1 = unpack_w(wB[c][kk]);
#pragma unroll
            for (int mt = 0; mt < 4; ++mt) {
                int row = mt*16 + l15;
                int ba  = (row*512 + kk*64 + lg*16) ^ ((row & 7) << 4);
                short8 af = *(const short8*)(xs + ba);   // conflict-free ds_read_b128
                acc[0][mt] = __builtin_amdgcn_mfma_f32_16x16x32_bf16(af, b0, acc[0][mt], 0, 0, 0);
                acc[1][mt] = __builtin_amdgcn_mfma_f32_16x16x32_bf16(af, b1, acc[1][mt], 0, 0, 0);
            }
        }
    }

    // ---- epilogue: scale, convert to bf16 partials, plain stores ----
    unsigned short* base = pw + (size_t)q * PARTF;
#pragma unroll
    for (int mt = 0; mt < 4; ++mt)
#pragma unroll
        for (int j = 0; j < 4; ++j) {
            int m = mt*16 + lg*4 + j;      // token index (D: row=(l>>4)*4+reg)
            base[(size_t)m*OUT_F + n0 + wv*32 + l15]      = f2bf(acc[0][mt][j]*sc0);
            base[(size_t)m*OUT_F + n0 + wv*32 + 16 + l15] = f2bf(acc[1][mt][j]*sc1);
        }
}

__global__ __launch_bounds__(256) void reduce_kernel(const unsigned short* __restrict__ pw,
                                                     float* __restrict__ out) {
    int i = blockIdx.x * 256 + threadIdx.x;     // short8 index, PARTF/8 = 88064 total
    float s[8];
#pragma unroll
    for (int e = 0; e < 8; ++e) s[e] = 0.f;
#pragma unroll
    for (int qq = 0; qq < KSPLIT; ++qq) {
        short8 v = ((const short8*)(pw + (size_t)qq*PARTF))[i];
#pragma unroll
        for (int e = 0; e < 8; ++e)
            s[e] += __uint_as_float(((uint32_t)(unsigned short)v[e]) << 16);
    }
    float4 o0 = {s[0], s[1], s[2], s[3]};
    float4 o1 = {s[4], s[5], s[6], s[7]};
    ((float4*)out)[2*i]   = o0;
    ((float4*)out)[2*i+1] = o1;
}

extern "C" void kernel_launch(void* const* d_in, const int* in_sizes, int n_in,
                              void* d_out, int out_size, void* d_ws, size_t ws_size,
                              hipStream_t stream) {
    const float*    x     = (const float*)d_in[0];
    const uint32_t* bp    = (const uint32_t*)d_in[1];
    const float*    scale = (const float*)d_in[2];
    unsigned short* pw = (unsigned short*)d_ws;   // 4 * 704512 * 2B = 5.6 MB partials

    gemm_kernel<<<dim3(NBLK*KSPLIT), dim3(256), 0, stream>>>(x, bp, scale, pw);
    reduce_kernel<<<dim3((PARTF/8)/256), dim3(256), 0, stream>>>(pw, (float*)d_out);
}